// Round 1
// baseline (143.543 us; speedup 1.0000x reference)
//
#include <hip/hip_runtime.h>
#include <hip/hip_bf16.h>

#define N_NODES 10000
#define N_EDGES 160000
#define D_IN 512
#define D_OUT 512
#define K_TOT 1024   // concat [x | neigh]

typedef __attribute__((ext_vector_type(8))) short short8;
typedef __attribute__((ext_vector_type(4))) float f32x4;

__device__ __forceinline__ void load_lds16(const void* g, void* l) {
    __builtin_amdgcn_global_load_lds(
        (const __attribute__((address_space(1))) void*)g,
        (__attribute__((address_space(3))) void*)l, 16, 0, 0);
}

// ---------------- CSR build ----------------

__global__ __launch_bounds__(256) void zero_deg_kernel(int* __restrict__ deg) {
    int i = blockIdx.x * 256 + threadIdx.x;
    if (i < N_NODES) deg[i] = 0;
}

__global__ __launch_bounds__(256) void count_kernel(const int* __restrict__ dst,
                                                    int* __restrict__ deg) {
    int e = blockIdx.x * 256 + threadIdx.x;
    if (e < N_EDGES) atomicAdd(&deg[dst[e]], 1);
}

__global__ __launch_bounds__(1024) void scan_kernel(const int* __restrict__ deg,
                                                    int* __restrict__ offsets,
                                                    int* __restrict__ cursor) {
    __shared__ int sd[1024];
    int tid = threadIdx.x;
    int running = 0;
    for (int c = 0; c < 10; ++c) {
        int i = c * 1024 + tid;
        int v = (i < N_NODES) ? deg[i] : 0;
        sd[tid] = v;
        __syncthreads();
        for (int off = 1; off < 1024; off <<= 1) {
            int t = (tid >= off) ? sd[tid - off] : 0;
            __syncthreads();
            sd[tid] += t;
            __syncthreads();
        }
        int excl = sd[tid] - v + running;
        if (i < N_NODES) { offsets[i] = excl; cursor[i] = excl; }
        running += sd[1023];
        __syncthreads();
    }
    if (tid == 0) offsets[N_NODES] = running;
}

__global__ __launch_bounds__(256) void scatter_kernel(const int* __restrict__ src,
                                                      const int* __restrict__ dst,
                                                      int* __restrict__ cursor,
                                                      int* __restrict__ csr_src) {
    int e = blockIdx.x * 256 + threadIdx.x;
    if (e < N_EDGES) {
        int p = atomicAdd(&cursor[dst[e]], 1);
        csr_src[p] = src[e];
    }
}

// ---------------- operand prep (f32 -> bf16) ----------------

// A[i][0:512] = bf16(x[i][:]);  thread handles 8 elems
__global__ __launch_bounds__(256) void convert_x_kernel(const float* __restrict__ x,
                                                        __hip_bfloat16* __restrict__ A) {
    int gid = blockIdx.x * 256 + threadIdx.x;          // 0 .. 640000
    int row = gid >> 6;                                 // 64 threads per row
    int col = (gid & 63) * 8;
    const float4* p = (const float4*)(x + (size_t)row * D_IN + col);
    float4 u = p[0], v = p[1];
    union { short8 s; __hip_bfloat16 h[8]; } o;
    o.h[0] = __float2bfloat16(u.x); o.h[1] = __float2bfloat16(u.y);
    o.h[2] = __float2bfloat16(u.z); o.h[3] = __float2bfloat16(u.w);
    o.h[4] = __float2bfloat16(v.x); o.h[5] = __float2bfloat16(v.y);
    o.h[6] = __float2bfloat16(v.z); o.h[7] = __float2bfloat16(v.w);
    *(short8*)(A + (size_t)row * K_TOT + col) = o.s;
}

// Wt[n][k] = bf16( k<512 ? W_self[k][n] : W_neigh[k-512][n] )
__global__ __launch_bounds__(256) void convert_w_kernel(const float* __restrict__ Wself,
                                                        const float* __restrict__ Wneigh,
                                                        __hip_bfloat16* __restrict__ Wt) {
    int gid = blockIdx.x * 256 + threadIdx.x;          // 0 .. 524288 over (n,k)
    int n = gid >> 10;
    int k = gid & 1023;
    float v = (k < D_IN) ? Wself[(size_t)k * D_OUT + n]
                         : Wneigh[(size_t)(k - D_IN) * D_OUT + n];
    Wt[(size_t)n * K_TOT + k] = __float2bfloat16(v);
}

// ---------------- aggregation: one wave per node ----------------

__global__ __launch_bounds__(256) void aggregate_kernel(const float* __restrict__ x,
                                                        const int* __restrict__ offsets,
                                                        const int* __restrict__ csr_src,
                                                        __hip_bfloat16* __restrict__ A) {
    int wave = threadIdx.x >> 6, lane = threadIdx.x & 63;
    int node = blockIdx.x * 4 + wave;
    if (node >= N_NODES) return;
    int e0 = offsets[node], e1 = offsets[node + 1];
    int d0 = lane * 8;
    float acc[8];
#pragma unroll
    for (int i = 0; i < 8; ++i) acc[i] = 0.f;
    for (int e = e0; e < e1; ++e) {
        int s = csr_src[e];
        const float4* p = (const float4*)(x + (size_t)s * D_IN + d0);
        float4 u = p[0], v = p[1];
        acc[0] += u.x; acc[1] += u.y; acc[2] += u.z; acc[3] += u.w;
        acc[4] += v.x; acc[5] += v.y; acc[6] += v.z; acc[7] += v.w;
    }
    float inv = 1.0f / fmaxf((float)(e1 - e0), 1.0f);
    union { short8 s; __hip_bfloat16 h[8]; } o;
#pragma unroll
    for (int i = 0; i < 8; ++i) o.h[i] = __float2bfloat16(acc[i] * inv);
    *(short8*)(A + (size_t)node * K_TOT + D_IN + d0) = o.s;
}

// ---------------- GEMM: C[10000][512] = A[10000][1024] @ Wt^T, + bias, leaky ----------------
// m97 structure: 128x128 tile, BK=32, 4 waves (2x2), 16x16x32 bf16 MFMA.

__global__ __launch_bounds__(256) void gemm_kernel(const short* __restrict__ A,
                                                   const short* __restrict__ Wt,
                                                   const float* __restrict__ bias,
                                                   float* __restrict__ H) {
    __shared__ __align__(16) short smA[128 * 32];
    __shared__ __align__(16) short smB[128 * 32];
    const int tid = threadIdx.x;
    const int wave = tid >> 6, lane = tid & 63;
    const int m0 = blockIdx.x * 128;
    const int n0 = blockIdx.y * 128;

    // staging: thread t -> 16B at LDS byte offset t*16 (per 4096B half): row=t/4, kcol=(t%4)*8
    const int srow = tid >> 2;
    const int skcol = (tid & 3) * 8;

    const int wm = wave >> 1, wn = wave & 1;
    const int rr = lane & 15, kq = lane >> 4;

    f32x4 acc[4][4];
#pragma unroll
    for (int i = 0; i < 4; ++i)
#pragma unroll
        for (int j = 0; j < 4; ++j) acc[i][j] = (f32x4){0.f, 0.f, 0.f, 0.f};

    int ra0 = m0 + srow;       if (ra0 > N_NODES - 1) ra0 = N_NODES - 1;
    int ra1 = m0 + 64 + srow;  if (ra1 > N_NODES - 1) ra1 = N_NODES - 1;
    const int rb0 = n0 + srow;           // < 512 always
    char* lA0 = (char*)smA + wave * 1024;
    char* lA1 = (char*)smA + 4096 + wave * 1024;
    char* lB0 = (char*)smB + wave * 1024;
    char* lB1 = (char*)smB + 4096 + wave * 1024;

    for (int kt = 0; kt < K_TOT / 32; ++kt) {
        const int k0 = kt * 32 + skcol;
        load_lds16(A + (size_t)ra0 * K_TOT + k0, lA0);
        load_lds16(A + (size_t)ra1 * K_TOT + k0, lA1);
        load_lds16(Wt + (size_t)rb0 * K_TOT + k0, lB0);
        load_lds16(Wt + (size_t)(rb0 + 64) * K_TOT + k0, lB1);
        __syncthreads();

        short8 afr[4], bfr[4];
#pragma unroll
        for (int mf = 0; mf < 4; ++mf)
            afr[mf] = *(const short8*)&smA[(wm * 64 + mf * 16 + rr) * 32 + kq * 8];
#pragma unroll
        for (int nf = 0; nf < 4; ++nf)
            bfr[nf] = *(const short8*)&smB[(wn * 64 + nf * 16 + rr) * 32 + kq * 8];
#pragma unroll
        for (int mf = 0; mf < 4; ++mf)
#pragma unroll
            for (int nf = 0; nf < 4; ++nf)
                acc[mf][nf] = __builtin_amdgcn_mfma_f32_16x16x32_bf16(
                    afr[mf], bfr[nf], acc[mf][nf], 0, 0, 0);
        __syncthreads();
    }

    // epilogue: bias + leaky_relu, store f32.  C/D: col=lane&15, row=(lane>>4)*4+reg
#pragma unroll
    for (int mf = 0; mf < 4; ++mf) {
        int row = m0 + wm * 64 + mf * 16 + kq * 4;
#pragma unroll
        for (int nf = 0; nf < 4; ++nf) {
            int col = n0 + wn * 64 + nf * 16 + rr;
            float bv = bias[col];
#pragma unroll
            for (int r = 0; r < 4; ++r) {
                int grow = row + r;
                if (grow < N_NODES) {
                    float v = acc[mf][nf][r] + bv;
                    v = (v >= 0.f) ? v : 0.01f * v;
                    H[(size_t)grow * D_OUT + col] = v;
                }
            }
        }
    }
}

// ---------------- row-wise L2 normalize (in place on d_out) ----------------

__global__ __launch_bounds__(256) void normalize_kernel(float* __restrict__ H) {
    int wave = threadIdx.x >> 6, lane = threadIdx.x & 63;
    int row = blockIdx.x * 4 + wave;
    if (row >= N_NODES) return;
    float4* p = (float4*)(H + (size_t)row * D_OUT + lane * 8);
    float4 u = p[0], v = p[1];
    float s = u.x * u.x + u.y * u.y + u.z * u.z + u.w * u.w +
              v.x * v.x + v.y * v.y + v.z * v.z + v.w * v.w;
#pragma unroll
    for (int o = 32; o > 0; o >>= 1) s += __shfl_xor(s, o);
    float scale = 1.0f / fmaxf(sqrtf(s), 1e-12f);
    u.x *= scale; u.y *= scale; u.z *= scale; u.w *= scale;
    v.x *= scale; v.y *= scale; v.z *= scale; v.w *= scale;
    p[0] = u; p[1] = v;
}

// ---------------- launch ----------------

extern "C" void kernel_launch(void* const* d_in, const int* in_sizes, int n_in,
                              void* d_out, int out_size, void* d_ws, size_t ws_size,
                              hipStream_t stream) {
    const float* x      = (const float*)d_in[0];
    const int*   src    = (const int*)d_in[1];
    const int*   dst    = (const int*)d_in[2];
    const float* Wself  = (const float*)d_in[3];
    const float* Wneigh = (const float*)d_in[4];
    const float* bias   = (const float*)d_in[5];
    float* H = (float*)d_out;

    char* ws = (char*)d_ws;
    int* deg     = (int*)ws;                 // 10000
    int* offsets = deg + N_NODES;            // 10001
    int* cursor  = offsets + N_NODES + 1;    // 10000
    int* csr_src = cursor + N_NODES;         // 160000
    size_t int_bytes = ((size_t)(N_NODES * 3 + 1 + N_EDGES) * 4 + 255) & ~(size_t)255;
    __hip_bfloat16* Abuf = (__hip_bfloat16*)(ws + int_bytes);        // [10000][1024]
    __hip_bfloat16* Wt   = Abuf + (size_t)N_NODES * K_TOT;           // [512][1024]

    zero_deg_kernel<<<(N_NODES + 255) / 256, 256, 0, stream>>>(deg);
    count_kernel<<<N_EDGES / 256, 256, 0, stream>>>(dst, deg);
    scan_kernel<<<1, 1024, 0, stream>>>(deg, offsets, cursor);
    scatter_kernel<<<N_EDGES / 256, 256, 0, stream>>>(src, dst, cursor, csr_src);

    convert_x_kernel<<<(N_NODES * D_IN / 8) / 256, 256, 0, stream>>>(x, Abuf);
    convert_w_kernel<<<(D_OUT * K_TOT) / 256, 256, 0, stream>>>(Wself, Wneigh, Wt);
    aggregate_kernel<<<(N_NODES + 3) / 4, 256, 0, stream>>>(x, offsets, csr_src, Abuf);

    dim3 ggrid((N_NODES + 127) / 128, D_OUT / 128);
    gemm_kernel<<<ggrid, 256, 0, stream>>>((const short*)Abuf, (const short*)Wt, bias, H);

    normalize_kernel<<<(N_NODES + 3) / 4, 256, 0, stream>>>(H);
}

// Round 2
// 114.102 us; speedup vs baseline: 1.2580x; 1.2580x over previous
//
#include <hip/hip_runtime.h>
#include <hip/hip_bf16.h>

#define N_NODES 10000
#define N_EDGES 160000
#define D_IN 512
#define D_OUT 512
#define K_TOT 1024   // concat [x | neigh]

typedef __attribute__((ext_vector_type(8))) short short8;
typedef __attribute__((ext_vector_type(4))) float f32x4;

__device__ __forceinline__ void load_lds16(const void* g, void* l) {
    __builtin_amdgcn_global_load_lds(
        (const __attribute__((address_space(1))) void*)g,
        (__attribute__((address_space(3))) void*)l, 16, 0, 0);
}

__device__ __forceinline__ float bf16_to_f32(unsigned short u) {
    union { unsigned int i; float f; } c;
    c.i = ((unsigned int)u) << 16;
    return c.f;
}

// ---------------- CSR build ----------------

__global__ __launch_bounds__(256) void zero_deg_kernel(int* __restrict__ deg) {
    int i = blockIdx.x * 256 + threadIdx.x;
    if (i < N_NODES) deg[i] = 0;
}

__global__ __launch_bounds__(256) void count_kernel(const int* __restrict__ dst,
                                                    int* __restrict__ deg) {
    int e = blockIdx.x * 256 + threadIdx.x;
    if (e < N_EDGES) atomicAdd(&deg[dst[e]], 1);
}

// single-block scan, shuffle-based (16 waves of 64)
__global__ __launch_bounds__(1024) void scan_kernel(const int* __restrict__ deg,
                                                    int* __restrict__ offsets,
                                                    int* __restrict__ cursor) {
    __shared__ int wsum[16];
    int tid = threadIdx.x, wave = tid >> 6, lane = tid & 63;
    int running = 0;
    for (int c = 0; c < 10; ++c) {
        int i = c * 1024 + tid;
        int v = (i < N_NODES) ? deg[i] : 0;
        int s = v;
#pragma unroll
        for (int off = 1; off < 64; off <<= 1) {
            int t = __shfl_up(s, off);
            if (lane >= off) s += t;
        }
        if (lane == 63) wsum[wave] = s;
        __syncthreads();
        if (wave == 0) {
            int w = (lane < 16) ? wsum[lane] : 0;
#pragma unroll
            for (int off = 1; off < 16; off <<= 1) {
                int t = __shfl_up(w, off);
                if (lane >= off) w += t;
            }
            if (lane < 16) wsum[lane] = w;   // inclusive wave totals
        }
        __syncthreads();
        int wprefix = (wave > 0) ? wsum[wave - 1] : 0;
        int excl = running + wprefix + s - v;
        if (i < N_NODES) { offsets[i] = excl; cursor[i] = excl; }
        running += wsum[15];
        __syncthreads();   // wsum reused next chunk
    }
    if (tid == 0) offsets[N_NODES] = running;
}

__global__ __launch_bounds__(256) void scatter_kernel(const int* __restrict__ src,
                                                      const int* __restrict__ dst,
                                                      int* __restrict__ cursor,
                                                      int* __restrict__ csr_src) {
    int e = blockIdx.x * 256 + threadIdx.x;
    if (e < N_EDGES) {
        int p = atomicAdd(&cursor[dst[e]], 1);
        csr_src[p] = src[e];
    }
}

// ---------------- operand prep (f32 -> bf16) ----------------

__global__ __launch_bounds__(256) void convert_x_kernel(const float* __restrict__ x,
                                                        __hip_bfloat16* __restrict__ A) {
    int gid = blockIdx.x * 256 + threadIdx.x;          // 0 .. 640000
    int row = gid >> 6;                                 // 64 threads per row
    int col = (gid & 63) * 8;
    const float4* p = (const float4*)(x + (size_t)row * D_IN + col);
    float4 u = p[0], v = p[1];
    union { short8 s; __hip_bfloat16 h[8]; } o;
    o.h[0] = __float2bfloat16(u.x); o.h[1] = __float2bfloat16(u.y);
    o.h[2] = __float2bfloat16(u.z); o.h[3] = __float2bfloat16(u.w);
    o.h[4] = __float2bfloat16(v.x); o.h[5] = __float2bfloat16(v.y);
    o.h[6] = __float2bfloat16(v.z); o.h[7] = __float2bfloat16(v.w);
    *(short8*)(A + (size_t)row * K_TOT + col) = o.s;
}

// Wt[n][k] = bf16( k<512 ? W_self[k][n] : W_neigh[k-512][n] )
__global__ __launch_bounds__(256) void convert_w_kernel(const float* __restrict__ Wself,
                                                        const float* __restrict__ Wneigh,
                                                        __hip_bfloat16* __restrict__ Wt) {
    int gid = blockIdx.x * 256 + threadIdx.x;          // 0 .. 524288 over (n,k)
    int n = gid >> 10;
    int k = gid & 1023;
    float v = (k < D_IN) ? Wself[(size_t)k * D_OUT + n]
                         : Wneigh[(size_t)(k - D_IN) * D_OUT + n];
    Wt[(size_t)n * K_TOT + k] = __float2bfloat16(v);
}

// ---------------- aggregation: one wave per node, bf16 gather ----------------
// Reads converted bf16 rows from A[s][0:512] (1KB/row), accumulates f32.

__global__ __launch_bounds__(256) void aggregate_kernel(const int* __restrict__ offsets,
                                                        const int* __restrict__ csr_src,
                                                        __hip_bfloat16* __restrict__ A) {
    int wave = threadIdx.x >> 6, lane = threadIdx.x & 63;
    int node = blockIdx.x * 4 + wave;
    if (node >= N_NODES) return;
    int e0 = offsets[node], e1 = offsets[node + 1];
    int d0 = lane * 8;                       // 8 bf16 per lane = 16B; 64 lanes = 1KB row
    const unsigned short* Au = (const unsigned short*)A;
    float acc[8];
#pragma unroll
    for (int i = 0; i < 8; ++i) acc[i] = 0.f;
    int e = e0;
    for (; e + 1 < e1; e += 2) {
        int s0 = csr_src[e], s1 = csr_src[e + 1];
        union { short8 v; unsigned short h[8]; } a, b;
        a.v = *(const short8*)(Au + (size_t)s0 * K_TOT + d0);
        b.v = *(const short8*)(Au + (size_t)s1 * K_TOT + d0);
#pragma unroll
        for (int i = 0; i < 8; ++i) acc[i] += bf16_to_f32(a.h[i]);
#pragma unroll
        for (int i = 0; i < 8; ++i) acc[i] += bf16_to_f32(b.h[i]);
    }
    if (e < e1) {
        int s0 = csr_src[e];
        union { short8 v; unsigned short h[8]; } a;
        a.v = *(const short8*)(Au + (size_t)s0 * K_TOT + d0);
#pragma unroll
        for (int i = 0; i < 8; ++i) acc[i] += bf16_to_f32(a.h[i]);
    }
    float inv = 1.0f / fmaxf((float)(e1 - e0), 1.0f);
    union { short8 s; __hip_bfloat16 h[8]; } o;
#pragma unroll
    for (int i = 0; i < 8; ++i) o.h[i] = __float2bfloat16(acc[i] * inv);
    *(short8*)(A + (size_t)node * K_TOT + D_IN + d0) = o.s;
}

// ---------------- GEMM: C[10000][512] = A[10000][1024] @ Wt^T, + bias, leaky ----------------
// m97 structure: 128x128 tile, BK=32, 4 waves (2x2), 16x16x32 bf16 MFMA.

__global__ __launch_bounds__(256) void gemm_kernel(const short* __restrict__ A,
                                                   const short* __restrict__ Wt,
                                                   const float* __restrict__ bias,
                                                   float* __restrict__ H) {
    __shared__ __align__(16) short smA[128 * 32];
    __shared__ __align__(16) short smB[128 * 32];
    const int tid = threadIdx.x;
    const int wave = tid >> 6, lane = tid & 63;
    const int m0 = blockIdx.x * 128;
    const int n0 = blockIdx.y * 128;

    const int srow = tid >> 2;
    const int skcol = (tid & 3) * 8;

    const int wm = wave >> 1, wn = wave & 1;
    const int rr = lane & 15, kq = lane >> 4;

    f32x4 acc[4][4];
#pragma unroll
    for (int i = 0; i < 4; ++i)
#pragma unroll
        for (int j = 0; j < 4; ++j) acc[i][j] = (f32x4){0.f, 0.f, 0.f, 0.f};

    int ra0 = m0 + srow;       if (ra0 > N_NODES - 1) ra0 = N_NODES - 1;
    int ra1 = m0 + 64 + srow;  if (ra1 > N_NODES - 1) ra1 = N_NODES - 1;
    const int rb0 = n0 + srow;
    char* lA0 = (char*)smA + wave * 1024;
    char* lA1 = (char*)smA + 4096 + wave * 1024;
    char* lB0 = (char*)smB + wave * 1024;
    char* lB1 = (char*)smB + 4096 + wave * 1024;

    for (int kt = 0; kt < K_TOT / 32; ++kt) {
        const int k0 = kt * 32 + skcol;
        load_lds16(A + (size_t)ra0 * K_TOT + k0, lA0);
        load_lds16(A + (size_t)ra1 * K_TOT + k0, lA1);
        load_lds16(Wt + (size_t)rb0 * K_TOT + k0, lB0);
        load_lds16(Wt + (size_t)(rb0 + 64) * K_TOT + k0, lB1);
        __syncthreads();

        short8 afr[4], bfr[4];
#pragma unroll
        for (int mf = 0; mf < 4; ++mf)
            afr[mf] = *(const short8*)&smA[(wm * 64 + mf * 16 + rr) * 32 + kq * 8];
#pragma unroll
        for (int nf = 0; nf < 4; ++nf)
            bfr[nf] = *(const short8*)&smB[(wn * 64 + nf * 16 + rr) * 32 + kq * 8];
#pragma unroll
        for (int mf = 0; mf < 4; ++mf)
#pragma unroll
            for (int nf = 0; nf < 4; ++nf)
                acc[mf][nf] = __builtin_amdgcn_mfma_f32_16x16x32_bf16(
                    afr[mf], bfr[nf], acc[mf][nf], 0, 0, 0);
        __syncthreads();
    }

#pragma unroll
    for (int mf = 0; mf < 4; ++mf) {
        int row = m0 + wm * 64 + mf * 16 + kq * 4;
#pragma unroll
        for (int nf = 0; nf < 4; ++nf) {
            int col = n0 + wn * 64 + nf * 16 + rr;
            float bv = bias[col];
#pragma unroll
            for (int r = 0; r < 4; ++r) {
                int grow = row + r;
                if (grow < N_NODES) {
                    float v = acc[mf][nf][r] + bv;
                    v = (v >= 0.f) ? v : 0.01f * v;
                    H[(size_t)grow * D_OUT + col] = v;
                }
            }
        }
    }
}

// ---------------- row-wise L2 normalize (in place on d_out) ----------------

__global__ __launch_bounds__(256) void normalize_kernel(float* __restrict__ H) {
    int wave = threadIdx.x >> 6, lane = threadIdx.x & 63;
    int row = blockIdx.x * 4 + wave;
    if (row >= N_NODES) return;
    float4* p = (float4*)(H + (size_t)row * D_OUT + lane * 8);
    float4 u = p[0], v = p[1];
    float s = u.x * u.x + u.y * u.y + u.z * u.z + u.w * u.w +
              v.x * v.x + v.y * v.y + v.z * v.z + v.w * v.w;
#pragma unroll
    for (int o = 32; o > 0; o >>= 1) s += __shfl_xor(s, o);
    float scale = 1.0f / fmaxf(sqrtf(s), 1e-12f);
    u.x *= scale; u.y *= scale; u.z *= scale; u.w *= scale;
    v.x *= scale; v.y *= scale; v.z *= scale; v.w *= scale;
    p[0] = u; p[1] = v;
}

// ---------------- launch ----------------

extern "C" void kernel_launch(void* const* d_in, const int* in_sizes, int n_in,
                              void* d_out, int out_size, void* d_ws, size_t ws_size,
                              hipStream_t stream) {
    const float* x      = (const float*)d_in[0];
    const int*   src    = (const int*)d_in[1];
    const int*   dst    = (const int*)d_in[2];
    const float* Wself  = (const float*)d_in[3];
    const float* Wneigh = (const float*)d_in[4];
    const float* bias   = (const float*)d_in[5];
    float* H = (float*)d_out;

    char* ws = (char*)d_ws;
    int* deg     = (int*)ws;                 // 10000
    int* offsets = deg + N_NODES;            // 10001
    int* cursor  = offsets + N_NODES + 1;    // 10000
    int* csr_src = cursor + N_NODES;         // 160000
    size_t int_bytes = ((size_t)(N_NODES * 3 + 1 + N_EDGES) * 4 + 255) & ~(size_t)255;
    __hip_bfloat16* Abuf = (__hip_bfloat16*)(ws + int_bytes);        // [10000][1024]
    __hip_bfloat16* Wt   = Abuf + (size_t)N_NODES * K_TOT;           // [512][1024]

    zero_deg_kernel<<<(N_NODES + 255) / 256, 256, 0, stream>>>(deg);
    count_kernel<<<N_EDGES / 256, 256, 0, stream>>>(dst, deg);
    scan_kernel<<<1, 1024, 0, stream>>>(deg, offsets, cursor);
    scatter_kernel<<<N_EDGES / 256, 256, 0, stream>>>(src, dst, cursor, csr_src);

    convert_x_kernel<<<(N_NODES * D_IN / 8) / 256, 256, 0, stream>>>(x, Abuf);
    convert_w_kernel<<<(D_OUT * K_TOT) / 256, 256, 0, stream>>>(Wself, Wneigh, Wt);
    aggregate_kernel<<<(N_NODES + 3) / 4, 256, 0, stream>>>(offsets, csr_src, Abuf);

    dim3 ggrid((N_NODES + 127) / 128, D_OUT / 128);
    gemm_kernel<<<ggrid, 256, 0, stream>>>((const short*)Abuf, (const short*)Wt, bias, H);

    normalize_kernel<<<(N_NODES + 3) / 4, 256, 0, stream>>>(H);
}

// Round 3
// 112.071 us; speedup vs baseline: 1.2808x; 1.0181x over previous
//
#include <hip/hip_runtime.h>
#include <hip/hip_bf16.h>

#define N_NODES 10000
#define N_EDGES 160000
#define D_IN 512
#define D_OUT 512
#define K_TOT 1024   // concat [x | neigh]

typedef __attribute__((ext_vector_type(8))) short short8;
typedef __attribute__((ext_vector_type(4))) float f32x4;

__device__ __forceinline__ void load_lds16(const void* g, void* l) {
    __builtin_amdgcn_global_load_lds(
        (const __attribute__((address_space(1))) void*)g,
        (__attribute__((address_space(3))) void*)l, 16, 0, 0);
}

__device__ __forceinline__ float bf16_to_f32(unsigned short u) {
    union { unsigned int i; float f; } c;
    c.i = ((unsigned int)u) << 16;
    return c.f;
}

// ---------------- CSR build ----------------

__global__ __launch_bounds__(256) void zero_deg_kernel(int* __restrict__ deg) {
    int i = blockIdx.x * 256 + threadIdx.x;
    if (i < N_NODES) deg[i] = 0;
}

__global__ __launch_bounds__(256) void count_kernel(const int* __restrict__ dst,
                                                    int* __restrict__ deg) {
    int e = blockIdx.x * 256 + threadIdx.x;
    if (e < N_EDGES) atomicAdd(&deg[dst[e]], 1);
}

// single-block scan, shuffle-based (16 waves of 64)
__global__ __launch_bounds__(1024) void scan_kernel(const int* __restrict__ deg,
                                                    int* __restrict__ offsets,
                                                    int* __restrict__ cursor) {
    __shared__ int wsum[16];
    int tid = threadIdx.x, wave = tid >> 6, lane = tid & 63;
    int running = 0;
    for (int c = 0; c < 10; ++c) {
        int i = c * 1024 + tid;
        int v = (i < N_NODES) ? deg[i] : 0;
        int s = v;
#pragma unroll
        for (int off = 1; off < 64; off <<= 1) {
            int t = __shfl_up(s, off);
            if (lane >= off) s += t;
        }
        if (lane == 63) wsum[wave] = s;
        __syncthreads();
        if (wave == 0) {
            int w = (lane < 16) ? wsum[lane] : 0;
#pragma unroll
            for (int off = 1; off < 16; off <<= 1) {
                int t = __shfl_up(w, off);
                if (lane >= off) w += t;
            }
            if (lane < 16) wsum[lane] = w;   // inclusive wave totals
        }
        __syncthreads();
        int wprefix = (wave > 0) ? wsum[wave - 1] : 0;
        int excl = running + wprefix + s - v;
        if (i < N_NODES) { offsets[i] = excl; cursor[i] = excl; }
        running += wsum[15];
        __syncthreads();   // wsum reused next chunk
    }
    if (tid == 0) offsets[N_NODES] = running;
}

__global__ __launch_bounds__(256) void scatter_kernel(const int* __restrict__ src,
                                                      const int* __restrict__ dst,
                                                      int* __restrict__ cursor,
                                                      int* __restrict__ csr_src) {
    int e = blockIdx.x * 256 + threadIdx.x;
    if (e < N_EDGES) {
        int p = atomicAdd(&cursor[dst[e]], 1);
        csr_src[p] = src[e];
    }
}

// ---------------- operand prep (f32 -> bf16) ----------------

__global__ __launch_bounds__(256) void convert_x_kernel(const float* __restrict__ x,
                                                        __hip_bfloat16* __restrict__ A) {
    int gid = blockIdx.x * 256 + threadIdx.x;          // 0 .. 640000
    int row = gid >> 6;                                 // 64 threads per row
    int col = (gid & 63) * 8;
    const float4* p = (const float4*)(x + (size_t)row * D_IN + col);
    float4 u = p[0], v = p[1];
    union { short8 s; __hip_bfloat16 h[8]; } o;
    o.h[0] = __float2bfloat16(u.x); o.h[1] = __float2bfloat16(u.y);
    o.h[2] = __float2bfloat16(u.z); o.h[3] = __float2bfloat16(u.w);
    o.h[4] = __float2bfloat16(v.x); o.h[5] = __float2bfloat16(v.y);
    o.h[6] = __float2bfloat16(v.z); o.h[7] = __float2bfloat16(v.w);
    *(short8*)(A + (size_t)row * K_TOT + col) = o.s;
}

// Wt[n][k] = bf16( k<512 ? W_self[k][n] : W_neigh[k-512][n] )
__global__ __launch_bounds__(256) void convert_w_kernel(const float* __restrict__ Wself,
                                                        const float* __restrict__ Wneigh,
                                                        __hip_bfloat16* __restrict__ Wt) {
    int gid = blockIdx.x * 256 + threadIdx.x;          // 0 .. 524288 over (n,k)
    int n = gid >> 10;
    int k = gid & 1023;
    float v = (k < D_IN) ? Wself[(size_t)k * D_OUT + n]
                         : Wneigh[(size_t)(k - D_IN) * D_OUT + n];
    Wt[(size_t)n * K_TOT + k] = __float2bfloat16(v);
}

// ---------------- aggregation: one wave per node, bf16 gather ----------------
// 64 edge indices loaded coalesced per wave, broadcast via shfl; 4 gathers in flight.

__global__ __launch_bounds__(256) void aggregate_kernel(const int* __restrict__ offsets,
                                                        const int* __restrict__ csr_src,
                                                        __hip_bfloat16* __restrict__ A) {
    int wave = threadIdx.x >> 6, lane = threadIdx.x & 63;
    int node = blockIdx.x * 4 + wave;
    if (node >= N_NODES) return;
    int e0 = offsets[node], e1 = offsets[node + 1];
    int cnt = e1 - e0;
    int d0 = lane * 8;                       // 8 bf16 per lane = 16B; 64 lanes = 1KB row
    const unsigned short* Au = (const unsigned short*)A;
    float acc[8];
#pragma unroll
    for (int i = 0; i < 8; ++i) acc[i] = 0.f;

    for (int base = 0; base < cnt; base += 64) {
        int m = cnt - base; if (m > 64) m = 64;
        int idx = (base + lane < cnt) ? csr_src[e0 + base + lane] : 0;
        int j = 0;
        for (; j + 3 < m; j += 4) {
            int s0 = __shfl(idx, j), s1 = __shfl(idx, j + 1);
            int s2 = __shfl(idx, j + 2), s3 = __shfl(idx, j + 3);
            union { short8 v; unsigned short h[8]; } a, b, c, d;
            a.v = *(const short8*)(Au + (size_t)s0 * K_TOT + d0);
            b.v = *(const short8*)(Au + (size_t)s1 * K_TOT + d0);
            c.v = *(const short8*)(Au + (size_t)s2 * K_TOT + d0);
            d.v = *(const short8*)(Au + (size_t)s3 * K_TOT + d0);
#pragma unroll
            for (int i = 0; i < 8; ++i) acc[i] += bf16_to_f32(a.h[i]);
#pragma unroll
            for (int i = 0; i < 8; ++i) acc[i] += bf16_to_f32(b.h[i]);
#pragma unroll
            for (int i = 0; i < 8; ++i) acc[i] += bf16_to_f32(c.h[i]);
#pragma unroll
            for (int i = 0; i < 8; ++i) acc[i] += bf16_to_f32(d.h[i]);
        }
        for (; j < m; ++j) {
            int s0 = __shfl(idx, j);
            union { short8 v; unsigned short h[8]; } a;
            a.v = *(const short8*)(Au + (size_t)s0 * K_TOT + d0);
#pragma unroll
            for (int i = 0; i < 8; ++i) acc[i] += bf16_to_f32(a.h[i]);
        }
    }
    float inv = 1.0f / fmaxf((float)cnt, 1.0f);
    union { short8 s; __hip_bfloat16 h[8]; } o;
#pragma unroll
    for (int i = 0; i < 8; ++i) o.h[i] = __float2bfloat16(acc[i] * inv);
    *(short8*)(A + (size_t)node * K_TOT + D_IN + d0) = o.s;
}

// ---------------- GEMM: C[10000][512] = A[10000][1024] @ Wt^T, + bias, leaky ----------------
// 128x64 tile, BK=32, 4 waves (2x2, each 64x32), 16x16x32 bf16 MFMA. 632 blocks.

__global__ __launch_bounds__(256) void gemm_kernel(const short* __restrict__ A,
                                                   const short* __restrict__ Wt,
                                                   const float* __restrict__ bias,
                                                   float* __restrict__ H) {
    __shared__ __align__(16) short smA[128 * 32];
    __shared__ __align__(16) short smB[64 * 32];
    const int tid = threadIdx.x;
    const int wave = tid >> 6, lane = tid & 63;
    const int m0 = blockIdx.x * 128;
    const int n0 = blockIdx.y * 64;

    const int srow = tid >> 2;            // 0..63
    const int skcol = (tid & 3) * 8;

    const int wm = wave >> 1, wn = wave & 1;
    const int rr = lane & 15, kq = lane >> 4;

    f32x4 acc[4][2];
#pragma unroll
    for (int i = 0; i < 4; ++i)
#pragma unroll
        for (int j = 0; j < 2; ++j) acc[i][j] = (f32x4){0.f, 0.f, 0.f, 0.f};

    int ra0 = m0 + srow;       if (ra0 > N_NODES - 1) ra0 = N_NODES - 1;
    int ra1 = m0 + 64 + srow;  if (ra1 > N_NODES - 1) ra1 = N_NODES - 1;
    const int rb0 = n0 + srow;            // < 512 always
    char* lA0 = (char*)smA + wave * 1024;
    char* lA1 = (char*)smA + 4096 + wave * 1024;
    char* lB0 = (char*)smB + wave * 1024;

    for (int kt = 0; kt < K_TOT / 32; ++kt) {
        const int k0 = kt * 32 + skcol;
        load_lds16(A + (size_t)ra0 * K_TOT + k0, lA0);
        load_lds16(A + (size_t)ra1 * K_TOT + k0, lA1);
        load_lds16(Wt + (size_t)rb0 * K_TOT + k0, lB0);
        __syncthreads();

        short8 afr[4], bfr[2];
#pragma unroll
        for (int mf = 0; mf < 4; ++mf)
            afr[mf] = *(const short8*)&smA[(wm * 64 + mf * 16 + rr) * 32 + kq * 8];
#pragma unroll
        for (int nf = 0; nf < 2; ++nf)
            bfr[nf] = *(const short8*)&smB[(wn * 32 + nf * 16 + rr) * 32 + kq * 8];
#pragma unroll
        for (int mf = 0; mf < 4; ++mf)
#pragma unroll
            for (int nf = 0; nf < 2; ++nf)
                acc[mf][nf] = __builtin_amdgcn_mfma_f32_16x16x32_bf16(
                    afr[mf], bfr[nf], acc[mf][nf], 0, 0, 0);
        __syncthreads();
    }

    // epilogue: bias + leaky_relu, store f32.  C/D: col=lane&15, row=(lane>>4)*4+reg
#pragma unroll
    for (int mf = 0; mf < 4; ++mf) {
        int row = m0 + wm * 64 + mf * 16 + kq * 4;
#pragma unroll
        for (int nf = 0; nf < 2; ++nf) {
            int col = n0 + wn * 32 + nf * 16 + rr;
            float bv = bias[col];
#pragma unroll
            for (int r = 0; r < 4; ++r) {
                int grow = row + r;
                if (grow < N_NODES) {
                    float v = acc[mf][nf][r] + bv;
                    v = (v >= 0.f) ? v : 0.01f * v;
                    H[(size_t)grow * D_OUT + col] = v;
                }
            }
        }
    }
}

// ---------------- row-wise L2 normalize (in place on d_out) ----------------

__global__ __launch_bounds__(256) void normalize_kernel(float* __restrict__ H) {
    int wave = threadIdx.x >> 6, lane = threadIdx.x & 63;
    int row = blockIdx.x * 4 + wave;
    if (row >= N_NODES) return;
    float4* p = (float4*)(H + (size_t)row * D_OUT + lane * 8);
    float4 u = p[0], v = p[1];
    float s = u.x * u.x + u.y * u.y + u.z * u.z + u.w * u.w +
              v.x * v.x + v.y * v.y + v.z * v.z + v.w * v.w;
#pragma unroll
    for (int o = 32; o > 0; o >>= 1) s += __shfl_xor(s, o);
    float scale = 1.0f / fmaxf(sqrtf(s), 1e-12f);
    u.x *= scale; u.y *= scale; u.z *= scale; u.w *= scale;
    v.x *= scale; v.y *= scale; v.z *= scale; v.w *= scale;
    p[0] = u; p[1] = v;
}

// ---------------- launch ----------------

extern "C" void kernel_launch(void* const* d_in, const int* in_sizes, int n_in,
                              void* d_out, int out_size, void* d_ws, size_t ws_size,
                              hipStream_t stream) {
    const float* x      = (const float*)d_in[0];
    const int*   src    = (const int*)d_in[1];
    const int*   dst    = (const int*)d_in[2];
    const float* Wself  = (const float*)d_in[3];
    const float* Wneigh = (const float*)d_in[4];
    const float* bias   = (const float*)d_in[5];
    float* H = (float*)d_out;

    char* ws = (char*)d_ws;
    int* deg     = (int*)ws;                 // 10000
    int* offsets = deg + N_NODES;            // 10001
    int* cursor  = offsets + N_NODES + 1;    // 10000
    int* csr_src = cursor + N_NODES;         // 160000
    size_t int_bytes = ((size_t)(N_NODES * 3 + 1 + N_EDGES) * 4 + 255) & ~(size_t)255;
    __hip_bfloat16* Abuf = (__hip_bfloat16*)(ws + int_bytes);        // [10000][1024]
    __hip_bfloat16* Wt   = Abuf + (size_t)N_NODES * K_TOT;           // [512][1024]

    zero_deg_kernel<<<(N_NODES + 255) / 256, 256, 0, stream>>>(deg);
    count_kernel<<<N_EDGES / 256, 256, 0, stream>>>(dst, deg);
    scan_kernel<<<1, 1024, 0, stream>>>(deg, offsets, cursor);
    scatter_kernel<<<N_EDGES / 256, 256, 0, stream>>>(src, dst, cursor, csr_src);

    convert_x_kernel<<<(N_NODES * D_IN / 8) / 256, 256, 0, stream>>>(x, Abuf);
    convert_w_kernel<<<(D_OUT * K_TOT) / 256, 256, 0, stream>>>(Wself, Wneigh, Wt);
    aggregate_kernel<<<(N_NODES + 3) / 4, 256, 0, stream>>>(offsets, csr_src, Abuf);

    dim3 ggrid((N_NODES + 127) / 128, D_OUT / 64);
    gemm_kernel<<<ggrid, 256, 0, stream>>>((const short*)Abuf, (const short*)Wt, bias, H);

    normalize_kernel<<<(N_NODES + 3) / 4, 256, 0, stream>>>(H);
}

// Round 4
// 105.923 us; speedup vs baseline: 1.3552x; 1.0580x over previous
//
#include <hip/hip_runtime.h>
#include <hip/hip_bf16.h>

#define N_NODES 10000
#define N_EDGES 160000
#define D_IN 512
#define D_OUT 512
#define K_TOT 1024   // concat [x | neigh]

typedef __attribute__((ext_vector_type(8))) short short8;
typedef __attribute__((ext_vector_type(4))) float f32x4;

__device__ __forceinline__ void load_lds16(const void* g, void* l) {
    __builtin_amdgcn_global_load_lds(
        (const __attribute__((address_space(1))) void*)g,
        (__attribute__((address_space(3))) void*)l, 16, 0, 0);
}

__device__ __forceinline__ float bf16_to_f32(unsigned short u) {
    union { unsigned int i; float f; } c;
    c.i = ((unsigned int)u) << 16;
    return c.f;
}

// ---------------- K1: count (blocks 0..624) + convert_w (blocks 625..2672) ----------------
// Wt[n][k] = bf16( k<512 ? W_self[k][n] : W_neigh[k-512][n] )

__global__ __launch_bounds__(256) void k1_count_convw(const int* __restrict__ dst,
                                                      int* __restrict__ deg,
                                                      const float* __restrict__ Wself,
                                                      const float* __restrict__ Wneigh,
                                                      __hip_bfloat16* __restrict__ Wt) {
    int bid = blockIdx.x;
    if (bid < 625) {
        int e = bid * 256 + threadIdx.x;          // exactly 160000
        atomicAdd(&deg[dst[e]], 1);
    } else {
        int gid = (bid - 625) * 256 + threadIdx.x; // exactly 524288 over (n,k)
        int n = gid >> 10;
        int k = gid & 1023;
        float v = (k < D_IN) ? Wself[(size_t)k * D_OUT + n]
                             : Wneigh[(size_t)(k - D_IN) * D_OUT + n];
        Wt[(size_t)n * K_TOT + k] = __float2bfloat16(v);
    }
}

// ---------------- K2: scan (block 0) + convert_x (blocks 1..625), 1024 threads ----------------

__global__ __launch_bounds__(1024) void k2_scan_convx(const int* __restrict__ deg,
                                                      int* __restrict__ offsets,
                                                      int* __restrict__ cursor,
                                                      const float* __restrict__ x,
                                                      __hip_bfloat16* __restrict__ A) {
    int bid = blockIdx.x;
    int tid = threadIdx.x;
    if (bid == 0) {
        // single-block shuffle scan over 10000 degrees
        __shared__ int wsum[16];
        int wave = tid >> 6, lane = tid & 63;
        int running = 0;
        for (int c = 0; c < 10; ++c) {
            int i = c * 1024 + tid;
            int v = (i < N_NODES) ? deg[i] : 0;
            int s = v;
#pragma unroll
            for (int off = 1; off < 64; off <<= 1) {
                int t = __shfl_up(s, off);
                if (lane >= off) s += t;
            }
            if (lane == 63) wsum[wave] = s;
            __syncthreads();
            if (wave == 0) {
                int w = (lane < 16) ? wsum[lane] : 0;
#pragma unroll
                for (int off = 1; off < 16; off <<= 1) {
                    int t = __shfl_up(w, off);
                    if (lane >= off) w += t;
                }
                if (lane < 16) wsum[lane] = w;
            }
            __syncthreads();
            int wprefix = (wave > 0) ? wsum[wave - 1] : 0;
            int excl = running + wprefix + s - v;
            if (i < N_NODES) { offsets[i] = excl; cursor[i] = excl; }
            running += wsum[15];
            __syncthreads();
        }
        if (tid == 0) offsets[N_NODES] = running;
    } else {
        int gid = (bid - 1) * 1024 + tid;          // exactly 640000
        int row = gid >> 6;
        int col = (gid & 63) * 8;
        const float4* p = (const float4*)(x + (size_t)row * D_IN + col);
        float4 u = p[0], v = p[1];
        union { short8 s; __hip_bfloat16 h[8]; } o;
        o.h[0] = __float2bfloat16(u.x); o.h[1] = __float2bfloat16(u.y);
        o.h[2] = __float2bfloat16(u.z); o.h[3] = __float2bfloat16(u.w);
        o.h[4] = __float2bfloat16(v.x); o.h[5] = __float2bfloat16(v.y);
        o.h[6] = __float2bfloat16(v.z); o.h[7] = __float2bfloat16(v.w);
        *(short8*)(A + (size_t)row * K_TOT + col) = o.s;
    }
}

// ---------------- K3: scatter ----------------

__global__ __launch_bounds__(256) void scatter_kernel(const int* __restrict__ src,
                                                      const int* __restrict__ dst,
                                                      int* __restrict__ cursor,
                                                      int* __restrict__ csr_src) {
    int e = blockIdx.x * 256 + threadIdx.x;       // exactly 160000
    int p = atomicAdd(&cursor[dst[e]], 1);
    csr_src[p] = src[e];
}

// ---------------- K4: aggregation — one wave per node, bf16 gather ----------------

__global__ __launch_bounds__(256) void aggregate_kernel(const int* __restrict__ offsets,
                                                        const int* __restrict__ csr_src,
                                                        __hip_bfloat16* __restrict__ A) {
    int wave = threadIdx.x >> 6, lane = threadIdx.x & 63;
    int node = blockIdx.x * 4 + wave;
    if (node >= N_NODES) return;
    int e0 = offsets[node], e1 = offsets[node + 1];
    int cnt = e1 - e0;
    int d0 = lane * 8;
    const unsigned short* Au = (const unsigned short*)A;
    float acc[8];
#pragma unroll
    for (int i = 0; i < 8; ++i) acc[i] = 0.f;

    for (int base = 0; base < cnt; base += 64) {
        int m = cnt - base; if (m > 64) m = 64;
        int idx = (base + lane < cnt) ? csr_src[e0 + base + lane] : 0;
        int j = 0;
        for (; j + 3 < m; j += 4) {
            int s0 = __shfl(idx, j), s1 = __shfl(idx, j + 1);
            int s2 = __shfl(idx, j + 2), s3 = __shfl(idx, j + 3);
            union { short8 v; unsigned short h[8]; } a, b, c, d;
            a.v = *(const short8*)(Au + (size_t)s0 * K_TOT + d0);
            b.v = *(const short8*)(Au + (size_t)s1 * K_TOT + d0);
            c.v = *(const short8*)(Au + (size_t)s2 * K_TOT + d0);
            d.v = *(const short8*)(Au + (size_t)s3 * K_TOT + d0);
#pragma unroll
            for (int i = 0; i < 8; ++i) acc[i] += bf16_to_f32(a.h[i]);
#pragma unroll
            for (int i = 0; i < 8; ++i) acc[i] += bf16_to_f32(b.h[i]);
#pragma unroll
            for (int i = 0; i < 8; ++i) acc[i] += bf16_to_f32(c.h[i]);
#pragma unroll
            for (int i = 0; i < 8; ++i) acc[i] += bf16_to_f32(d.h[i]);
        }
        for (; j < m; ++j) {
            int s0 = __shfl(idx, j);
            union { short8 v; unsigned short h[8]; } a;
            a.v = *(const short8*)(Au + (size_t)s0 * K_TOT + d0);
#pragma unroll
            for (int i = 0; i < 8; ++i) acc[i] += bf16_to_f32(a.h[i]);
        }
    }
    float inv = 1.0f / fmaxf((float)cnt, 1.0f);
    union { short8 s; __hip_bfloat16 h[8]; } o;
#pragma unroll
    for (int i = 0; i < 8; ++i) o.h[i] = __float2bfloat16(acc[i] * inv);
    *(short8*)(A + (size_t)node * K_TOT + D_IN + d0) = o.s;
}

// ---------------- K5: fused GEMM + bias + leaky + row L2-normalize ----------------
// Tile BM=32 x BN=512 (full row per block), BK=32, 4 waves; wave w owns cols w*128..+127.
// A read once; B (1MB) re-read per block but L2-resident.

__global__ __launch_bounds__(256, 2) void gemm_norm_kernel(const short* __restrict__ A,
                                                           const short* __restrict__ Wt,
                                                           const float* __restrict__ bias,
                                                           float* __restrict__ H) {
    __shared__ __align__(16) short smA[32 * 32];        // 2 KB
    __shared__ __align__(16) short smB[512 * 32];       // 32 KB
    __shared__ float sqlds[4][32];

    const int tid = threadIdx.x;
    const int wave = tid >> 6, lane = tid & 63;
    const int m0 = blockIdx.x * 32;
    const int rr = lane & 15, kq = lane >> 4;

    f32x4 acc[2][8];
#pragma unroll
    for (int i = 0; i < 2; ++i)
#pragma unroll
        for (int j = 0; j < 8; ++j) acc[i][j] = (f32x4){0.f, 0.f, 0.f, 0.f};

    // staging coords
    const int arow_l = tid >> 2;                 // 0..63 (only tid<128 used for A)
    const int kc = (tid & 3) * 8;
    int arow = m0 + arow_l; if (arow > N_NODES - 1) arow = N_NODES - 1;
    const int brow = tid >> 2;                   // 0..63, + seg*64

    char* ldsA = (char*)smA + wave * 1024;       // waves 0,1 only
    char* ldsB0 = (char*)smB + wave * 1024;      // + seg*4096

    // bias per lane for its 8 col-fragments
    float bvs[8];
#pragma unroll
    for (int nf = 0; nf < 8; ++nf) bvs[nf] = bias[wave * 128 + nf * 16 + rr];

    for (int kt = 0; kt < K_TOT / 32; ++kt) {
        const int k0 = kt * 32 + kc;
        if (tid < 128)
            load_lds16(A + (size_t)arow * K_TOT + k0, ldsA);
#pragma unroll
        for (int s = 0; s < 8; ++s)
            load_lds16(Wt + (size_t)(s * 64 + brow) * K_TOT + k0, ldsB0 + s * 4096);
        __syncthreads();

        short8 afr[2], bfr[8];
#pragma unroll
        for (int mf = 0; mf < 2; ++mf)
            afr[mf] = *(const short8*)&smA[(mf * 16 + rr) * 32 + kq * 8];
#pragma unroll
        for (int nf = 0; nf < 8; ++nf)
            bfr[nf] = *(const short8*)&smB[(wave * 128 + nf * 16 + rr) * 32 + kq * 8];
#pragma unroll
        for (int mf = 0; mf < 2; ++mf)
#pragma unroll
            for (int nf = 0; nf < 8; ++nf)
                acc[mf][nf] = __builtin_amdgcn_mfma_f32_16x16x32_bf16(
                    afr[mf], bfr[nf], acc[mf][nf], 0, 0, 0);
        __syncthreads();
    }

    // epilogue: bias + leaky, row sumsq, normalize, store
    float sq[2][4];
#pragma unroll
    for (int mf = 0; mf < 2; ++mf)
#pragma unroll
        for (int r = 0; r < 4; ++r) sq[mf][r] = 0.f;

#pragma unroll
    for (int mf = 0; mf < 2; ++mf)
#pragma unroll
        for (int nf = 0; nf < 8; ++nf)
#pragma unroll
            for (int r = 0; r < 4; ++r) {
                float v = acc[mf][nf][r] + bvs[nf];
                v = (v >= 0.f) ? v : 0.01f * v;
                acc[mf][nf][r] = v;
                sq[mf][r] += v * v;
            }

    // reduce across the 16 rr-lanes (same kq group)
#pragma unroll
    for (int o = 1; o < 16; o <<= 1)
#pragma unroll
        for (int mf = 0; mf < 2; ++mf)
#pragma unroll
            for (int r = 0; r < 4; ++r) sq[mf][r] += __shfl_xor(sq[mf][r], o);

    if (rr == 0) {
#pragma unroll
        for (int mf = 0; mf < 2; ++mf)
#pragma unroll
            for (int r = 0; r < 4; ++r)
                sqlds[wave][mf * 16 + kq * 4 + r] = sq[mf][r];
    }
    __syncthreads();

    float scl[2][4];
#pragma unroll
    for (int mf = 0; mf < 2; ++mf)
#pragma unroll
        for (int r = 0; r < 4; ++r) {
            int row = mf * 16 + kq * 4 + r;
            float tot = sqlds[0][row] + sqlds[1][row] + sqlds[2][row] + sqlds[3][row];
            scl[mf][r] = 1.0f / fmaxf(sqrtf(tot), 1e-12f);
        }

#pragma unroll
    for (int mf = 0; mf < 2; ++mf)
#pragma unroll
        for (int r = 0; r < 4; ++r) {
            int grow = m0 + mf * 16 + kq * 4 + r;
            if (grow < N_NODES) {
#pragma unroll
                for (int nf = 0; nf < 8; ++nf)
                    H[(size_t)grow * D_OUT + wave * 128 + nf * 16 + rr] =
                        acc[mf][nf][r] * scl[mf][r];
            }
        }
}

// ---------------- launch ----------------

extern "C" void kernel_launch(void* const* d_in, const int* in_sizes, int n_in,
                              void* d_out, int out_size, void* d_ws, size_t ws_size,
                              hipStream_t stream) {
    const float* x      = (const float*)d_in[0];
    const int*   src    = (const int*)d_in[1];
    const int*   dst    = (const int*)d_in[2];
    const float* Wself  = (const float*)d_in[3];
    const float* Wneigh = (const float*)d_in[4];
    const float* bias   = (const float*)d_in[5];
    float* H = (float*)d_out;

    char* ws = (char*)d_ws;
    int* deg     = (int*)ws;                 // 10000
    int* offsets = deg + N_NODES;            // 10001
    int* cursor  = offsets + N_NODES + 1;    // 10000
    int* csr_src = cursor + N_NODES;         // 160000
    size_t int_bytes = ((size_t)(N_NODES * 3 + 1 + N_EDGES) * 4 + 255) & ~(size_t)255;
    __hip_bfloat16* Abuf = (__hip_bfloat16*)(ws + int_bytes);        // [10000][1024]
    __hip_bfloat16* Wt   = Abuf + (size_t)N_NODES * K_TOT;           // [512][1024]

    hipMemsetAsync(deg, 0, N_NODES * sizeof(int), stream);

    k1_count_convw<<<625 + 2048, 256, 0, stream>>>(dst, deg, Wself, Wneigh, Wt);
    k2_scan_convx<<<626, 1024, 0, stream>>>(deg, offsets, cursor, x, Abuf);
    scatter_kernel<<<625, 256, 0, stream>>>(src, dst, cursor, csr_src);
    aggregate_kernel<<<2500, 256, 0, stream>>>(offsets, csr_src, Abuf);
    gemm_norm_kernel<<<313, 256, 0, stream>>>((const short*)Abuf, (const short*)Wt, bias, H);
}

// Round 5
// 104.201 us; speedup vs baseline: 1.3776x; 1.0165x over previous
//
#include <hip/hip_runtime.h>
#include <hip/hip_bf16.h>

#define N_NODES 10000
#define N_EDGES 160000
#define D_IN 512
#define D_OUT 512
#define K_TOT 1024   // concat [x | neigh]
#define BK 64

typedef __attribute__((ext_vector_type(8))) short short8;
typedef __attribute__((ext_vector_type(4))) float f32x4;

__device__ __forceinline__ void load_lds16(const void* g, void* l) {
    __builtin_amdgcn_global_load_lds(
        (const __attribute__((address_space(1))) void*)g,
        (__attribute__((address_space(3))) void*)l, 16, 0, 0);
}

__device__ __forceinline__ float bf16_to_f32(unsigned short u) {
    union { unsigned int i; float f; } c;
    c.i = ((unsigned int)u) << 16;
    return c.f;
}

// ---------------- K1: count (blocks 0..624) + W transpose (blocks 625..1136) ----------------
// Wt[n][k] = bf16( k<512 ? W_self[k][n] : W_neigh[k-512][n] ), via LDS 32x32 tiles.

__global__ __launch_bounds__(256) void k1_count_convw(const int* __restrict__ dst,
                                                      int* __restrict__ deg,
                                                      const float* __restrict__ Wself,
                                                      const float* __restrict__ Wneigh,
                                                      __hip_bfloat16* __restrict__ Wt) {
    int bid = blockIdx.x;
    if (bid < 625) {
        int e = bid * 256 + threadIdx.x;          // exactly 160000
        atomicAdd(&deg[dst[e]], 1);
        return;
    }
    // transpose tile: 512 blocks over (k-tile 32, n-tile 16): b = (bid-625)
    __shared__ float tl[32][33];
    int b = bid - 625;
    int kt0 = (b & 31) * 32;          // k tile base, 0..1023
    int nt0 = (b >> 5) * 32;          // n tile base, 0..511
    int tx = threadIdx.x & 31, ty = threadIdx.x >> 5;   // ty 0..7
    const float* Wsrc = (kt0 < D_IN) ? (Wself + (size_t)kt0 * D_OUT)
                                     : (Wneigh + (size_t)(kt0 - D_IN) * D_OUT);
#pragma unroll
    for (int p = 0; p < 4; ++p)
        tl[p * 8 + ty][tx] = Wsrc[(size_t)(p * 8 + ty) * D_OUT + nt0 + tx];
    __syncthreads();
#pragma unroll
    for (int p = 0; p < 4; ++p)
        Wt[(size_t)(nt0 + p * 8 + ty) * K_TOT + kt0 + tx] =
            __float2bfloat16(tl[tx][p * 8 + ty]);
}

// ---------------- K2: scan (block 0) + convert_x (blocks 1..625), 1024 threads ----------------

__global__ __launch_bounds__(1024) void k2_scan_convx(const int* __restrict__ deg,
                                                      int* __restrict__ offsets,
                                                      int* __restrict__ cursor,
                                                      const float* __restrict__ x,
                                                      __hip_bfloat16* __restrict__ A) {
    int bid = blockIdx.x;
    int tid = threadIdx.x;
    if (bid == 0) {
        __shared__ int wsum[16];
        int wave = tid >> 6, lane = tid & 63;
        int running = 0;
        for (int c = 0; c < 10; ++c) {
            int i = c * 1024 + tid;
            int v = (i < N_NODES) ? deg[i] : 0;
            int s = v;
#pragma unroll
            for (int off = 1; off < 64; off <<= 1) {
                int t = __shfl_up(s, off);
                if (lane >= off) s += t;
            }
            if (lane == 63) wsum[wave] = s;
            __syncthreads();
            if (wave == 0) {
                int w = (lane < 16) ? wsum[lane] : 0;
#pragma unroll
                for (int off = 1; off < 16; off <<= 1) {
                    int t = __shfl_up(w, off);
                    if (lane >= off) w += t;
                }
                if (lane < 16) wsum[lane] = w;
            }
            __syncthreads();
            int wprefix = (wave > 0) ? wsum[wave - 1] : 0;
            int excl = running + wprefix + s - v;
            if (i < N_NODES) { offsets[i] = excl; cursor[i] = excl; }
            running += wsum[15];
            __syncthreads();
        }
        if (tid == 0) offsets[N_NODES] = running;
    } else {
        int gid = (bid - 1) * 1024 + tid;          // exactly 640000
        int row = gid >> 6;
        int col = (gid & 63) * 8;
        const float4* p = (const float4*)(x + (size_t)row * D_IN + col);
        float4 u = p[0], v = p[1];
        union { short8 s; __hip_bfloat16 h[8]; } o;
        o.h[0] = __float2bfloat16(u.x); o.h[1] = __float2bfloat16(u.y);
        o.h[2] = __float2bfloat16(u.z); o.h[3] = __float2bfloat16(u.w);
        o.h[4] = __float2bfloat16(v.x); o.h[5] = __float2bfloat16(v.y);
        o.h[6] = __float2bfloat16(v.z); o.h[7] = __float2bfloat16(v.w);
        *(short8*)(A + (size_t)row * K_TOT + col) = o.s;
    }
}

// ---------------- K3: scatter ----------------

__global__ __launch_bounds__(256) void scatter_kernel(const int* __restrict__ src,
                                                      const int* __restrict__ dst,
                                                      int* __restrict__ cursor,
                                                      int* __restrict__ csr_src) {
    int e = blockIdx.x * 256 + threadIdx.x;       // exactly 160000
    int p = atomicAdd(&cursor[dst[e]], 1);
    csr_src[p] = src[e];
}

// ---------------- K4: aggregation — one wave per node, bf16 gather ----------------

__global__ __launch_bounds__(256) void aggregate_kernel(const int* __restrict__ offsets,
                                                        const int* __restrict__ csr_src,
                                                        __hip_bfloat16* __restrict__ A) {
    int wave = threadIdx.x >> 6, lane = threadIdx.x & 63;
    int node = blockIdx.x * 4 + wave;
    if (node >= N_NODES) return;
    int e0 = offsets[node], e1 = offsets[node + 1];
    int cnt = e1 - e0;
    int d0 = lane * 8;
    const unsigned short* Au = (const unsigned short*)A;
    float acc[8];
#pragma unroll
    for (int i = 0; i < 8; ++i) acc[i] = 0.f;

    for (int base = 0; base < cnt; base += 64) {
        int m = cnt - base; if (m > 64) m = 64;
        int idx = (base + lane < cnt) ? csr_src[e0 + base + lane] : 0;
        int j = 0;
        for (; j + 3 < m; j += 4) {
            int s0 = __shfl(idx, j), s1 = __shfl(idx, j + 1);
            int s2 = __shfl(idx, j + 2), s3 = __shfl(idx, j + 3);
            union { short8 v; unsigned short h[8]; } a, b, c, d;
            a.v = *(const short8*)(Au + (size_t)s0 * K_TOT + d0);
            b.v = *(const short8*)(Au + (size_t)s1 * K_TOT + d0);
            c.v = *(const short8*)(Au + (size_t)s2 * K_TOT + d0);
            d.v = *(const short8*)(Au + (size_t)s3 * K_TOT + d0);
#pragma unroll
            for (int i = 0; i < 8; ++i) acc[i] += bf16_to_f32(a.h[i]);
#pragma unroll
            for (int i = 0; i < 8; ++i) acc[i] += bf16_to_f32(b.h[i]);
#pragma unroll
            for (int i = 0; i < 8; ++i) acc[i] += bf16_to_f32(c.h[i]);
#pragma unroll
            for (int i = 0; i < 8; ++i) acc[i] += bf16_to_f32(d.h[i]);
        }
        for (; j < m; ++j) {
            int s0 = __shfl(idx, j);
            union { short8 v; unsigned short h[8]; } a;
            a.v = *(const short8*)(Au + (size_t)s0 * K_TOT + d0);
#pragma unroll
            for (int i = 0; i < 8; ++i) acc[i] += bf16_to_f32(a.h[i]);
        }
    }
    float inv = 1.0f / fmaxf((float)cnt, 1.0f);
    union { short8 s; __hip_bfloat16 h[8]; } o;
#pragma unroll
    for (int i = 0; i < 8; ++i) o.h[i] = __float2bfloat16(acc[i] * inv);
    *(short8*)(A + (size_t)node * K_TOT + D_IN + d0) = o.s;
}

// ---------------- K5: GEMM 128x64 tile, BK=64, swizzled LDS (conflict-free) ----------------
// Swizzle (rule #21 both-sides): linear LDS dest via global_load_lds; lane l of each
// 1KB wave-load fetches global 16B-chunk (l&7)^(l>>3) of row l>>3; fragment reads use
// slot = (ks*4+kq) ^ (row&7).  => 16 lanes cover 8 slots = 2-way = free.

__global__ __launch_bounds__(256, 2) void gemm_kernel(const short* __restrict__ A,
                                                      const short* __restrict__ Wt,
                                                      const float* __restrict__ bias,
                                                      float* __restrict__ H) {
    __shared__ __align__(16) short smA[128 * BK];   // 16 KB, rows of 128B
    __shared__ __align__(16) short smB[64 * BK];    // 8 KB
    const int tid = threadIdx.x;
    const int wave = tid >> 6, lane = tid & 63;
    const int m0 = blockIdx.x * 128;
    const int n0 = blockIdx.y * 64;
    const int wm = wave >> 1, wn = wave & 1;
    const int rr = lane & 15, kq = lane >> 4;

    const int srow8 = lane >> 3;            // row within 8-row chunk
    const int sslot = (lane & 7) ^ srow8;   // pre-swizzled global 16B-chunk index

    f32x4 acc[4][2];
#pragma unroll
    for (int i = 0; i < 4; ++i)
#pragma unroll
        for (int j = 0; j < 2; ++j) acc[i][j] = (f32x4){0.f, 0.f, 0.f, 0.f};

    // A chunk rows (clamped)
    int garow[4];
#pragma unroll
    for (int i = 0; i < 4; ++i) {
        int g = m0 + (wave + 4 * i) * 8 + srow8;
        garow[i] = (g > N_NODES - 1) ? N_NODES - 1 : g;
    }
    int gbrow[2];
#pragma unroll
    for (int i = 0; i < 2; ++i) gbrow[i] = n0 + (wave + 4 * i) * 8 + srow8;   // < 512

    for (int kt = 0; kt < K_TOT / BK; ++kt) {
        const int kbase = kt * BK + sslot * 8;
#pragma unroll
        for (int i = 0; i < 4; ++i)
            load_lds16(A + (size_t)garow[i] * K_TOT + kbase,
                       (char*)smA + (wave + 4 * i) * 1024);
#pragma unroll
        for (int i = 0; i < 2; ++i)
            load_lds16(Wt + (size_t)gbrow[i] * K_TOT + kbase,
                       (char*)smB + (wave + 4 * i) * 1024);
        __syncthreads();

        short8 afr[2][4], bfr[2][2];
#pragma unroll
        for (int ks = 0; ks < 2; ++ks) {
#pragma unroll
            for (int mf = 0; mf < 4; ++mf) {
                int row = wm * 64 + mf * 16 + rr;
                int slot = (ks * 4 + kq) ^ (row & 7);
                afr[ks][mf] = *(const short8*)&smA[row * 64 + slot * 8];
            }
#pragma unroll
            for (int nf = 0; nf < 2; ++nf) {
                int row = wn * 32 + nf * 16 + rr;
                int slot = (ks * 4 + kq) ^ (row & 7);
                bfr[ks][nf] = *(const short8*)&smB[row * 64 + slot * 8];
            }
        }
#pragma unroll
        for (int ks = 0; ks < 2; ++ks)
#pragma unroll
            for (int mf = 0; mf < 4; ++mf)
#pragma unroll
                for (int nf = 0; nf < 2; ++nf)
                    acc[mf][nf] = __builtin_amdgcn_mfma_f32_16x16x32_bf16(
                        afr[ks][mf], bfr[ks][nf], acc[mf][nf], 0, 0, 0);
        __syncthreads();
    }

    // epilogue: bias + leaky_relu, store f32.  C/D: col=lane&15, row=(lane>>4)*4+reg
#pragma unroll
    for (int mf = 0; mf < 4; ++mf) {
        int row = m0 + wm * 64 + mf * 16 + kq * 4;
#pragma unroll
        for (int nf = 0; nf < 2; ++nf) {
            int col = n0 + wn * 32 + nf * 16 + rr;
            float bv = bias[col];
#pragma unroll
            for (int r = 0; r < 4; ++r) {
                int grow = row + r;
                if (grow < N_NODES) {
                    float v = acc[mf][nf][r] + bv;
                    v = (v >= 0.f) ? v : 0.01f * v;
                    H[(size_t)grow * D_OUT + col] = v;
                }
            }
        }
    }
}

// ---------------- K6: row-wise L2 normalize (in place on d_out) ----------------

__global__ __launch_bounds__(256) void normalize_kernel(float* __restrict__ H) {
    int wave = threadIdx.x >> 6, lane = threadIdx.x & 63;
    int row = blockIdx.x * 4 + wave;
    if (row >= N_NODES) return;
    float4* p = (float4*)(H + (size_t)row * D_OUT + lane * 8);
    float4 u = p[0], v = p[1];
    float s = u.x * u.x + u.y * u.y + u.z * u.z + u.w * u.w +
              v.x * v.x + v.y * v.y + v.z * v.z + v.w * v.w;
#pragma unroll
    for (int o = 32; o > 0; o >>= 1) s += __shfl_xor(s, o);
    float scale = 1.0f / fmaxf(sqrtf(s), 1e-12f);
    u.x *= scale; u.y *= scale; u.z *= scale; u.w *= scale;
    v.x *= scale; v.y *= scale; v.z *= scale; v.w *= scale;
    p[0] = u; p[1] = v;
}

// ---------------- launch ----------------

extern "C" void kernel_launch(void* const* d_in, const int* in_sizes, int n_in,
                              void* d_out, int out_size, void* d_ws, size_t ws_size,
                              hipStream_t stream) {
    const float* x      = (const float*)d_in[0];
    const int*   src    = (const int*)d_in[1];
    const int*   dst    = (const int*)d_in[2];
    const float* Wself  = (const float*)d_in[3];
    const float* Wneigh = (const float*)d_in[4];
    const float* bias   = (const float*)d_in[5];
    float* H = (float*)d_out;

    char* ws = (char*)d_ws;
    int* deg     = (int*)ws;                 // 10000
    int* offsets = deg + N_NODES;            // 10001
    int* cursor  = offsets + N_NODES + 1;    // 10000
    int* csr_src = cursor + N_NODES;         // 160000
    size_t int_bytes = ((size_t)(N_NODES * 3 + 1 + N_EDGES) * 4 + 255) & ~(size_t)255;
    __hip_bfloat16* Abuf = (__hip_bfloat16*)(ws + int_bytes);        // [10000][1024]
    __hip_bfloat16* Wt   = Abuf + (size_t)N_NODES * K_TOT;           // [512][1024]

    hipMemsetAsync(deg, 0, N_NODES * sizeof(int), stream);

    k1_count_convw<<<625 + 512, 256, 0, stream>>>(dst, deg, Wself, Wneigh, Wt);
    k2_scan_convx<<<626, 1024, 0, stream>>>(deg, offsets, cursor, x, Abuf);
    scatter_kernel<<<625, 256, 0, stream>>>(src, dst, cursor, csr_src);
    aggregate_kernel<<<2500, 256, 0, stream>>>(offsets, csr_src, Abuf);

    dim3 ggrid((N_NODES + 127) / 128, D_OUT / 64);
    gemm_kernel<<<ggrid, 256, 0, stream>>>((const short*)Abuf, (const short*)Wt, bias, H);

    normalize_kernel<<<2500, 256, 0, stream>>>(H);
}